// Round 3
// baseline (767.903 us; speedup 1.0000x reference)
//
#include <hip/hip_runtime.h>

// Problem: B=2, H=4, S=4096, D=64.  q,k,v fp32; mask int32.
// Outputs (fp32, concat): out [2,4,4096,64] then attn [2,4,4096,4096].
#define SDIM 4096
#define DDIM 64
#define HDIM 4
#define OUTN (2 * HDIM * SDIM * DDIM)   // 2,097,152 floats of `out`
#define NZ 4                            // t-range split (grid.z)

typedef short short8 __attribute__((ext_vector_type(8)));  // 8 x bf16
typedef float f32x4  __attribute__((ext_vector_type(4)));

__device__ inline short f2bf(float f) {
    unsigned u = __builtin_bit_cast(unsigned, f);
    u = (u + 0x7fffu + ((u >> 16) & 1u)) >> 16;
    return (short)u;
}

// async global->LDS DMA, 16 B per lane; LDS dest = (uniform base) + lane*16
__device__ inline void gload_lds16(const short* g, short* l) {
    __builtin_amdgcn_global_load_lds(
        (const __attribute__((address_space(1))) void*)g,
        (__attribute__((address_space(3))) void*)l, 16, 0, 0);
}

// ---------------------------------------------------------------------------
// Pre-pass 1: bit-pack mask (1,S,S) int32 -> 1 bit/elem (2 MB in ws).
__global__ void pack_mask(const int* __restrict__ mask,
                          unsigned long long* __restrict__ bits) {
    int gid = blockIdx.x * 256 + threadIdx.x;
    int v = (mask[gid] != 0);
    unsigned long long bal = __ballot(v);
    if ((threadIdx.x & 63) == 0) bits[gid >> 6] = bal;
}

// ---------------------------------------------------------------------------
// Pre-pass 2: fp32 -> bf16 (Q and K).
__global__ void cvt_bf16(const float* __restrict__ src, short* __restrict__ dst) {
    int gid = blockIdx.x * 256 + threadIdx.x;
    const float* p = src + (size_t)gid * 8;
    f32x4 a = *(const f32x4*)p;
    f32x4 b = *(const f32x4*)(p + 4);
    short8 o;
#pragma unroll
    for (int j = 0; j < 4; ++j) { o[j] = f2bf(a[j]); o[j + 4] = f2bf(b[j]); }
    *(short8*)(dst + (size_t)gid * 8) = o;
}

// ---------------------------------------------------------------------------
// Pre-pass 3: VT[b][h][d][t] = bf16(V[b][h][t][d]).
__global__ void transpose_v(const float* __restrict__ v, short* __restrict__ vt) {
    int gid = blockIdx.x * 256 + threadIdx.x;
    int t8 = gid & (SDIM / 8 - 1);
    int d  = (gid >> 9) & (DDIM - 1);
    int bh = gid >> 15;
    short8 o;
#pragma unroll
    for (int j = 0; j < 8; ++j)
        o[j] = f2bf(v[((size_t)bh * SDIM + t8 * 8 + j) * DDIM + d]);
    *(short8*)(vt + ((size_t)bh * DDIM + d) * SDIM + t8 * 8) = o;
}

// ---------------------------------------------------------------------------
// Fused: block = (head h, 64 q-rows, both batches, 1/NZ of t).
// LDS layout: 64 rows x 8 chunks(16B); chunk swizzled by XOR(row&7) so the
// lane-contiguous global_load_lds write and the b128 fragment reads are both
// conflict-free. Ks is reused as the P tile after barrier C.
__global__ __launch_bounds__(256, 2)
void attn_fused(const short* __restrict__ qg, const short* __restrict__ kg,
                const short* __restrict__ vtg,
                const unsigned long long* __restrict__ mbits,
                float* __restrict__ attng, float* __restrict__ opart) {
    __shared__ short Ks [2][64 * 64];   // K tile; becomes P tile after QK
    __shared__ short VTs[2][64 * 64];   // V^T tile (rows = d)

    const int h   = blockIdx.y;
    const int s0  = blockIdx.x << 6;
    const int tz  = blockIdx.z;
    const int tid = threadIdx.x;
    const int wv  = tid >> 6;
    const int ln  = tid & 63;
    const int l   = ln & 15;
    const int qd  = ln >> 4;

    // Q A-fragments (A[m=lane&15][k=quad*8+j]), in registers for whole kernel
    short8 qf[2][2];
#pragma unroll
    for (int b = 0; b < 2; ++b) {
        const size_t rb = ((size_t)(b * HDIM + h) * SDIM + (s0 + wv * 16 + l)) * DDIM;
#pragma unroll
        for (int kc = 0; kc < 2; ++kc)
            qf[b][kc] = *(const short8*)(qg + rb + kc * 32 + qd * 8);
    }

    f32x4 oacc[2][4];
#pragma unroll
    for (int b = 0; b < 2; ++b)
#pragma unroll
        for (int nd = 0; nd < 4; ++nd)
            oacc[b][nd] = (f32x4){0.f, 0.f, 0.f, 0.f};

    // staging: wave w owns one 8 KB region (Ks0,Ks1,VT0,VT1); 8 pieces x 1 KB
    const int prow = ln >> 3;                 // row within piece
    const int pcol = ln & 7;                  // physical 16B chunk
    const int sb   = wv & 1;                  // staging batch
    short* lb = (wv < 2) ? &Ks[sb][0] : &VTs[sb][0];

    const int mrow0 = s0 + wv * 16 + qd * 4;  // this quad's first C row
    const int tbeg  = tz * (SDIM / NZ);

    for (int t0 = tbeg; t0 < tbeg + SDIM / NZ; t0 += 64) {
        __syncthreads();                      // A: prev-iter LDS reads done

        unsigned long long mw[4];
#pragma unroll
        for (int rg = 0; rg < 4; ++rg)
            mw[rg] = mbits[(size_t)(mrow0 + rg) * (SDIM / 64) + (t0 >> 6)];

        if (wv < 2) {                         // K rows t0..t0+63, 128 B each
            const short* kb = kg + ((size_t)(sb * HDIM + h) * SDIM + t0) * DDIM;
#pragma unroll
            for (int q = 0; q < 8; ++q) {
                int row = q * 8 + prow;
                int c   = pcol ^ (row & 7);   // load the chunk that lands swizzled
                gload_lds16(kb + row * DDIM + c * 8, lb + q * 512);
            }
        } else {                              // V^T rows d=0..63, stride S
            const short* vb = vtg + ((size_t)(sb * HDIM + h) * DDIM) * SDIM + t0;
#pragma unroll
            for (int q = 0; q < 8; ++q) {
                int row = q * 8 + prow;
                int c   = pcol ^ (row & 7);
                gload_lds16(vb + (size_t)row * SDIM + c * 8, lb + q * 512);
            }
        }
        __syncthreads();                      // B: staging visible

        // QK^T: B[k][n]=K[n][k]; row n=nt*16+l, chunk kc*4+qd (swizzled)
        f32x4 sc[2][4];
#pragma unroll
        for (int b = 0; b < 2; ++b)
#pragma unroll
            for (int nt = 0; nt < 4; ++nt) {
                f32x4 acc = (f32x4){0.f, 0.f, 0.f, 0.f};
#pragma unroll
                for (int kc = 0; kc < 2; ++kc) {
                    const short8 bf = *(const short8*)
                        (&Ks[b][(nt * 16 + l) * 64 + (((kc * 4 + qd) ^ (l & 7)) << 3)]);
                    acc = __builtin_amdgcn_mfma_f32_16x16x32_bf16(qf[b][kc], bf, acc, 0, 0, 0);
                }
                sc[b][nt] = acc;
            }

        // batch-pair softmax, fp32 in regs (p0 -> sc[0], p1 -> sc[1])
#pragma unroll
        for (int nt = 0; nt < 4; ++nt)
#pragma unroll
            for (int rg = 0; rg < 4; ++rg) {
                float dd = (sc[0][nt][rg] - sc[1][nt][rg]) * 0.125f;
                bool msk = (mw[rg] >> (nt * 16 + l)) & 1ull;
                float p0 = msk ? 0.5f : __builtin_amdgcn_rcpf(1.f + __expf(-dd));
                sc[0][nt][rg] = p0;
                sc[1][nt][rg] = 1.f - p0;
            }

        __syncthreads();                      // C: all QK reads of Ks done

        // P (bf16) -> Ks region, swizzled scatter (C layout: row=qd*4+rg, col=nt*16+l)
#pragma unroll
        for (int b = 0; b < 2; ++b)
#pragma unroll
            for (int nt = 0; nt < 4; ++nt)
#pragma unroll
                for (int rg = 0; rg < 4; ++rg) {
                    int row = wv * 16 + qd * 4 + rg;
                    int col = nt * 16 + l;
                    Ks[b][row * 64 + (((col >> 3) ^ (row & 7)) << 3) + (col & 7)] =
                        f2bf(sc[b][nt][rg]);
                }

        // attn: direct fp32 stores from C regs (16 lanes -> 64 B segment/row)
#pragma unroll
        for (int b = 0; b < 2; ++b) {
            size_t ab = ((size_t)(b * HDIM + h) * SDIM + mrow0) * (size_t)SDIM + t0;
#pragma unroll
            for (int nt = 0; nt < 4; ++nt)
#pragma unroll
                for (int rg = 0; rg < 4; ++rg)
                    __builtin_nontemporal_store(sc[b][nt][rg],
                        attng + ab + (size_t)rg * SDIM + nt * 16 + l);
        }

        // PV: A = own P strip (same-wave DS ordering), B = V^T rows
#pragma unroll
        for (int b = 0; b < 2; ++b)
#pragma unroll
            for (int kc = 0; kc < 2; ++kc) {
                const short8 af = *(const short8*)
                    (&Ks[b][(wv * 16 + l) * 64 + (((kc * 4 + qd) ^ (l & 7)) << 3)]);
#pragma unroll
                for (int nd = 0; nd < 4; ++nd) {
                    const short8 bf = *(const short8*)
                        (&VTs[b][(nd * 16 + l) * 64 + (((kc * 4 + qd) ^ (l & 7)) << 3)]);
                    oacc[b][nd] = __builtin_amdgcn_mfma_f32_16x16x32_bf16(af, bf, oacc[b][nd], 0, 0, 0);
                }
            }
    }

    // epilogue: partial O -> ws (C layout: col=lane&15, row=quad*4+reg)
#pragma unroll
    for (int b = 0; b < 2; ++b)
#pragma unroll
        for (int nd = 0; nd < 4; ++nd)
#pragma unroll
            for (int rg = 0; rg < 4; ++rg) {
                int srow = s0 + wv * 16 + qd * 4 + rg;
                opart[(size_t)tz * OUTN +
                      ((size_t)(b * HDIM + h) * SDIM + srow) * DDIM + nd * 16 + l] =
                    oacc[b][nd][rg];
            }
}

// ---------------------------------------------------------------------------
// Sum the NZ t-range partials into out.
__global__ void combine(const float* __restrict__ opart, float* __restrict__ outg) {
    int gid = blockIdx.x * 256 + threadIdx.x;           // OUTN/4 threads
    f32x4 s = (f32x4){0.f, 0.f, 0.f, 0.f};
#pragma unroll
    for (int z = 0; z < NZ; ++z)
        s += *(const f32x4*)(opart + (size_t)z * OUTN + (size_t)gid * 4);
    *(f32x4*)(outg + (size_t)gid * 4) = s;
}

// ---------------------------------------------------------------------------
extern "C" void kernel_launch(void* const* d_in, const int* in_sizes, int n_in,
                              void* d_out, int out_size, void* d_ws, size_t ws_size,
                              hipStream_t stream) {
    (void)in_sizes; (void)n_in; (void)out_size; (void)ws_size;
    const float* qg  = (const float*)d_in[0];
    const float* kg  = (const float*)d_in[1];
    const float* vg  = (const float*)d_in[2];
    const int*   msk = (const int*)d_in[3];

    float* outg  = (float*)d_out;
    float* attng = outg + (size_t)OUTN;

    char* ws = (char*)d_ws;
    unsigned long long* bits = (unsigned long long*)ws;            // 2 MB
    short* qb = (short*)(ws + (size_t) 2 * 1024 * 1024);           // 4 MB
    short* kb = (short*)(ws + (size_t) 6 * 1024 * 1024);           // 4 MB
    short* vt = (short*)(ws + (size_t)10 * 1024 * 1024);           // 4 MB
    float* op = (float*)(ws + (size_t)14 * 1024 * 1024);           // NZ*8 MB

    pack_mask  <<<dim3(SDIM * SDIM / 256), dim3(256), 0, stream>>>(msk, bits);
    cvt_bf16   <<<dim3(OUTN / (8 * 256)), dim3(256), 0, stream>>>(qg, qb);
    cvt_bf16   <<<dim3(OUTN / (8 * 256)), dim3(256), 0, stream>>>(kg, kb);
    transpose_v<<<dim3(OUTN / (8 * 256)), dim3(256), 0, stream>>>(vg, vt);
    attn_fused <<<dim3(SDIM / 64, HDIM, NZ), dim3(256), 0, stream>>>(qb, kb, vt, bits, attng, op);
    combine    <<<dim3(OUTN / (4 * 256)), dim3(256), 0, stream>>>(op, outg);
}